// Round 13
// baseline (341.138 us; speedup 1.0000x reference)
//
#include <hip/hip_runtime.h>
#include <hip/hip_bf16.h>
#include <math.h>

typedef __hip_bfloat16 bf16;
typedef short short8 __attribute__((ext_vector_type(8)));
typedef float f32x4 __attribute__((ext_vector_type(4)));

__device__ __forceinline__ float b2f(const bf16 v) { return __bfloat162float(v); }
__device__ __forceinline__ bf16 f2b(const float v) { return __float2bfloat16(v); }

// raw-bits bf16 -> f32
__device__ __forceinline__ float bits2f(short s) {
  unsigned u = ((unsigned)(unsigned short)s) << 16;
  float f;
  __builtin_memcpy(&f, &u, 4);
  return f;
}
__device__ __forceinline__ short f2bits(float f) {
  bf16 b = f2b(f);
  short s;
  __builtin_memcpy(&s, &b, 2);
  return s;
}

// dtype-flexible load/store: f32 flag selects float32 vs bfloat16 interpretation
__device__ __forceinline__ float ldsel(const void* p, size_t i, int f32) {
  return f32 ? ((const float*)p)[i] : b2f(((const bf16*)p)[i]);
}
__device__ __forceinline__ void stsel(void* p, size_t i, float v, int f32) {
  if (f32) ((float*)p)[i] = v; else ((bf16*)p)[i] = f2b(v);
}

// vectorized 8-wide dtype-flexible load
__device__ __forceinline__ void load8f(const void* p, int idx, int f32, float* o) {
  if (f32) {
    const float4* q = (const float4*)((const float*)p + idx);
    float4 a = q[0], b = q[1];
    o[0] = a.x; o[1] = a.y; o[2] = a.z; o[3] = a.w;
    o[4] = b.x; o[5] = b.y; o[6] = b.z; o[7] = b.w;
  } else {
    union { short8 v; short s[8]; } u;
    u.v = *(const short8*)((const bf16*)p + idx);
#pragma unroll
    for (int j = 0; j < 8; ++j) o[j] = bits2f(u.s[j]);
  }
}

#define NN 3712          // nodes
#define NE 37120         // edges (without self loops)
#define NG 32            // graphs
#define NREG 116         // nodes per graph
#define MAXDEG 48        // bucket capacity

// ---------------------------------------------------------------------------
// GLOBAL NODE->XCD PARTITION (verified R8: -57us): XCD x owns nodes
// [464x, 464(x+1)); (bid & 7) == owning XCD everywhere.
// R12 BUG (absmax 3.35): hoisting w1/w2 transposes to prep2 was clobbered —
// wt1/wt2 live inside Hb, and gemm0's C covers ALL of Hb. R13 FIX: the w1/w2
// transposes are role-blocks appended to the PRECEDING layer's k_ln grid
// (after the last Hb reader, before the consuming gemm). Dispatches stay 15.
// ---------------------------------------------------------------------------

// ---------------- prep1: dtype detect || cnt zero ----------------
__global__ __launch_bounds__(256) void k_prep1(const void* nf, const void* w0,
                                               int* flags, int* cnt) {
  if (blockIdx.x == 0) {
    __shared__ int bad[2];
    if (threadIdx.x < 2) bad[threadIdx.x] = 0;
    __syncthreads();
    const bf16* a = (const bf16*)nf;
    const bf16* b = (const bf16*)w0;
    int l0 = 0, l1 = 0;
    for (int i = threadIdx.x; i < 4096; i += 256) {
      float x = b2f(a[i]); if (!(fabsf(x) < 1e4f)) l0++;
      float y = b2f(b[i]); if (!(fabsf(y) < 1e4f)) l1++;
    }
    if (l0) atomicAdd(&bad[0], l0);
    if (l1) atomicAdd(&bad[1], l1);
    __syncthreads();
    if (threadIdx.x == 0) { flags[0] = bad[0] > 0; flags[1] = bad[1] > 0; }
  } else {
    int i = (blockIdx.x - 1) * 256 + threadIdx.x;
    if (i < NN) cnt[i] = 0;
  }
}

// 32x32 transpose tile worker (all threads of a block take the same role branch)
__device__ __forceinline__ void dev_transpose(const void* W, bf16* Wt, int K, int N,
                                              int bx, int by, int f, float tile[32][33]) {
  int tx = threadIdx.x & 31, ty = threadIdx.x >> 5;
  int k0 = bx * 32, n0 = by * 32;
#pragma unroll
  for (int i = 0; i < 4; ++i)
    tile[ty + i * 8][tx] = ldsel(W, (size_t)(k0 + ty + i * 8) * N + n0 + tx, f);
  __syncthreads();
#pragma unroll
  for (int i = 0; i < 4; ++i)
    Wt[(size_t)(n0 + ty + i * 8) * K + k0 + tx] = f2b(tile[tx][ty + i * 8]);
}

// ---------------- prep2: scatter || tox0 || w0 transpose || al/ar zero ----------------
// All roles independent; depend only on prep1. wt0 lives in the X region (safe:
// gemm0 is its only consumer and nothing writes X before gemm0).
// Grid = 145 + 3712 + 512 + 116 = 4485.
__global__ __launch_bounds__(256) void k_prep2(const int* __restrict__ src, const int* __restrict__ dst,
    int* __restrict__ cnt, int* __restrict__ bucket, const void* __restrict__ nf, bf16* __restrict__ X0,
    const void* __restrict__ w0, bf16* __restrict__ wt0, float* __restrict__ al, float* __restrict__ ar,
    const int* __restrict__ flags) {
  __shared__ float tile[32][33];
  int id = blockIdx.x, t = threadIdx.x;
  if (id < 145) {                                   // edge scatter (NE = 145*256)
    int e = id * 256 + t;
    if (e < NE) {
      int d = dst[e], s = src[e];
      if ((unsigned)d < NN && (unsigned)s < NN) {
        int p = atomicAdd(&cnt[d], 1);
        if (p < MAXDEG) bucket[d * MAXDEG + p] = s;
      }
    }
  } else if ((id -= 145) < NN) {                    // input -> bf16, partition-aligned
    int f = flags[0];
    int n = (id & 7) * 464 + (id >> 3);
    int i = n * 256 + t;
    X0[i] = f2b(ldsel(nf, i, f));
  } else if ((id -= NN) < 512) {                    // w0: 256 x 2048
    dev_transpose(w0, wt0, 256, 2048, id & 7, id >> 3, flags[1], tile);
  } else {                                          // zero al/ar for layer-0 gemm atomics
    id -= 512;
    int i = id * 256 + t;
    if (i < NN * 8) { al[i] = 0.f; ar[i] = 0.f; }
  }
}

// ---------------- MFMA bf16 NT GEMM + fused attention-coefficient epilogue ----------------
// C[MxN] = A[MxK] * Bt[NxK]^T; 64x64 tile, BK=64, 4 waves (2x2).
// Chunk swizzle == global node partition. Epilogue (R12): while the H-tile is
// still in fp32 registers, accumulate al/ar partials (dot with a_src/a_dst)
// via ml-lane shfl reduce + atomicAdd. Head is block-uniform (64 | Chead).
__global__ __launch_bounds__(256) void k_gemm_mfma(const bf16* __restrict__ A, const bf16* __restrict__ Bt,
                                                   bf16* __restrict__ C, int M, int N, int K,
                                                   const void* __restrict__ a_s, const void* __restrict__ a_d,
                                                   float* __restrict__ al, float* __restrict__ ar,
                                                   int Chead, const int* __restrict__ flags) {
  __shared__ short As[64 * 72];
  __shared__ short Bs[64 * 72];
  int tid = threadIdx.x;
  int wave = tid >> 6, lane = tid & 63;
  int wr = wave >> 1, wc = wave & 1;
  int quad = lane >> 4, ml = lane & 15;

  int nbx = N >> 6;
  int total = gridDim.x;
  int id = blockIdx.x;
  int tile = ((total & 7) == 0) ? ((id & 7) * (total >> 3) + (id >> 3)) : id;
  int n0 = (tile % nbx) << 6;
  int m0 = (tile / nbx) << 6;

  f32x4 acc[2][2];
#pragma unroll
  for (int rt = 0; rt < 2; ++rt)
#pragma unroll
    for (int ct = 0; ct < 2; ++ct)
#pragma unroll
      for (int r = 0; r < 4; ++r) acc[rt][ct][r] = 0.f;

  for (int k0 = 0; k0 < K; k0 += 64) {
    __syncthreads();
#pragma unroll
    for (int i = 0; i < 2; ++i) {
      int c = tid + (i << 8);
      int row = c >> 3, kg = (c & 7) << 3;
      *(uint4*)&As[row * 72 + kg] = *(const uint4*)&A[(size_t)(m0 + row) * K + k0 + kg];
      *(uint4*)&Bs[row * 72 + kg] = *(const uint4*)&Bt[(size_t)(n0 + row) * K + k0 + kg];
    }
    __syncthreads();
    short8 af[2][2], bfr[2][2];
#pragma unroll
    for (int rt = 0; rt < 2; ++rt)
#pragma unroll
      for (int kk = 0; kk < 2; ++kk)
        af[rt][kk] = *(const short8*)&As[(wr * 32 + rt * 16 + ml) * 72 + kk * 32 + quad * 8];
#pragma unroll
    for (int ct = 0; ct < 2; ++ct)
#pragma unroll
      for (int kk = 0; kk < 2; ++kk)
        bfr[ct][kk] = *(const short8*)&Bs[(wc * 32 + ct * 16 + ml) * 72 + kk * 32 + quad * 8];
#pragma unroll
    for (int rt = 0; rt < 2; ++rt)
#pragma unroll
      for (int ct = 0; ct < 2; ++ct)
#pragma unroll
        for (int kk = 0; kk < 2; ++kk)
          acc[rt][ct] = __builtin_amdgcn_mfma_f32_16x16x32_bf16(af[rt][kk], bfr[ct][kk], acc[rt][ct], 0, 0, 0);
  }
  // store C tile
#pragma unroll
  for (int rt = 0; rt < 2; ++rt)
#pragma unroll
    for (int ct = 0; ct < 2; ++ct)
#pragma unroll
      for (int r = 0; r < 4; ++r) {
        int grow = m0 + wr * 32 + rt * 16 + quad * 4 + r;
        int gcol = n0 + wc * 32 + ct * 16 + ml;
        C[(size_t)grow * N + gcol] = f2b(acc[rt][ct][r]);
      }

  // fused attention-coefficient epilogue
  int wF = flags[1];
  int hd = n0 / Chead;                               // block-uniform head
  float asv[2], adv[2];
#pragma unroll
  for (int ct = 0; ct < 2; ++ct) {
    int gcol = n0 + wc * 32 + ct * 16 + ml;
    asv[ct] = ldsel(a_s, gcol, wF);
    adv[ct] = ldsel(a_d, gcol, wF);
  }
  float pal[8], par[8];
#pragma unroll
  for (int k = 0; k < 8; ++k) { pal[k] = 0.f; par[k] = 0.f; }
#pragma unroll
  for (int rt = 0; rt < 2; ++rt)
#pragma unroll
    for (int ct = 0; ct < 2; ++ct)
#pragma unroll
      for (int r = 0; r < 4; ++r) {
        int k = rt * 4 + r;
        pal[k] = fmaf(acc[rt][ct][r], asv[ct], pal[k]);
        par[k] = fmaf(acc[rt][ct][r], adv[ct], par[k]);
      }
#pragma unroll
  for (int off = 1; off < 16; off <<= 1) {
#pragma unroll
    for (int k = 0; k < 8; ++k) {
      pal[k] += __shfl_xor(pal[k], off);
      par[k] += __shfl_xor(par[k], off);
    }
  }
  if (ml == 0) {
#pragma unroll
    for (int rt = 0; rt < 2; ++rt)
#pragma unroll
      for (int r = 0; r < 4; ++r) {
        int grow = m0 + wr * 32 + rt * 16 + quad * 4 + r;
        atomicAdd(&al[grow * 8 + hd], pal[rt * 4 + r]);
        atomicAdd(&ar[grow * 8 + hd], par[rt * 4 + r]);
      }
  }
}

// ---------------- per-(dst,head) softmax max & 1/denominator ----------------
__global__ __launch_bounds__(256) void k_edgew(const float* __restrict__ al, const float* __restrict__ ar,
                                               const int* __restrict__ cnt, const int* __restrict__ bucket,
                                               float* __restrict__ mbuf, float* __restrict__ ibuf) {
  int t = threadIdx.x;
  int q = t >> 6, l = t & 63, hd = l >> 3, el = l & 7;
  int bid = blockIdx.x;                    // grid 928 = 8 * 116
  int d = (bid & 7) * 464 + (bid >> 3) * 4 + q;
  int deg = cnt[d]; deg = deg > MAXDEG ? MAXDEG : deg;
  int total = deg + 1;
  float ard = ar[d * 8 + hd];
  float lgv[7];
  float m = -1e30f;
#pragma unroll
  for (int k = 0; k < 7; ++k) {
    int e = el + k * 8;
    float lg = -1e30f;
    if (e < total) {
      int s = e < deg ? bucket[d * MAXDEG + e] : d;
      lg = al[s * 8 + hd] + ard;
      lg = lg > 0.f ? lg : 0.2f * lg;
    }
    lgv[k] = lg;
    m = fmaxf(m, lg);
  }
#pragma unroll
  for (int off = 4; off; off >>= 1) m = fmaxf(m, __shfl_xor(m, off));
  float den = 0.f;
#pragma unroll
  for (int k = 0; k < 7; ++k) den += (lgv[k] > -1e29f) ? expf(lgv[k] - m) : 0.f;
#pragma unroll
  for (int off = 4; off; off >>= 1) den += __shfl_xor(den, off);
  if (el == 0) { mbuf[d * 8 + hd] = m; ibuf[d * 8 + hd] = 1.f / den; }
}

// ---------------- MFMA aggregation: per (graph, head) block ----------------
// X_g[dst, h*C:...] = P_gh (116x116, LDS, bf16) @ H_g[:, h*C:...] (LDS, transposed).
// R11-verified: Ht column XOR-swizzle SW(c,s) = s ^ (((c>>3)&15)<<3) kills the
// 32-way transposed-staging bank conflict (7.7M -> ~0 cycles).
template<int C>
__global__ __launch_bounds__(256, 1) void k_aggm(const bf16* __restrict__ H,
    const float* __restrict__ al, const float* __restrict__ ar,
    const float* __restrict__ mbuf, const float* __restrict__ ibuf,
    const int* __restrict__ cnt, const int* __restrict__ bucket,
    bf16* __restrict__ Y) {
  constexpr int D = 8 * C;
  constexpr int KP = 136;                 // padded K row (shorts)
  __shared__ short P[128 * KP];
  __shared__ short Ht[C * KP];
  int t = threadIdx.x;
  int bid = blockIdx.x;                   // grid 256 = 8 XCD * 4 graphs * 8 heads
  int x = bid & 7, j = bid >> 3;
  int g = x * 4 + (j & 3);
  int h = j >> 2;
  int gbase = g * NREG;

  short8 z = {0, 0, 0, 0, 0, 0, 0, 0};
  for (int i = t; i < 128 * KP / 8; i += 256) *(short8*)&P[i * 8] = z;
  for (int i = t; i < C * 12; i += 256) {
    int c = i / 12, s = 116 + i % 12;
    Ht[c * KP + (s ^ (((c >> 3) & 15) << 3))] = 0;
  }
  __syncthreads();

  constexpr int CH = C / 8;
  for (int idx = t; idx < NREG * CH; idx += 256) {
    int s = idx / CH, c0 = (idx % CH) * 8;
    int msk = ((idx % CH) & 15) << 3;
    int sw = s ^ msk;
    union { short8 v; short x2[8]; } u;
    u.v = *(const short8*)&H[(size_t)(gbase + s) * D + h * C + c0];
#pragma unroll
    for (int jj = 0; jj < 8; ++jj) Ht[(c0 + jj) * KP + sw] = u.x2[jj];
  }
  if (t < NREG) {
    int gd = gbase + t;
    int deg = cnt[gd]; deg = deg > MAXDEG ? MAXDEG : deg;
    int total = deg + 1;
    float ard = ar[gd * 8 + h];
    float mm = mbuf[gd * 8 + h], inv = ibuf[gd * 8 + h];
    for (int base = 0; base < total; base += 8) {
      int sg[8]; float av[8];
#pragma unroll
      for (int jj = 0; jj < 8; ++jj) {
        int e = base + jj;
        sg[jj] = (e < deg) ? bucket[gd * MAXDEG + e] : gd;
      }
#pragma unroll
      for (int jj = 0; jj < 8; ++jj) av[jj] = al[sg[jj] * 8 + h];
#pragma unroll
      for (int jj = 0; jj < 8; ++jj) {
        if (base + jj < total) {
          float lg = av[jj] + ard;
          lg = lg > 0.f ? lg : 0.2f * lg;
          float alpha = expf(lg - mm) * inv;
          int off = t * KP + (sg[jj] - gbase);
          P[off] = f2bits(bits2f(P[off]) + alpha);
        }
      }
    }
  }
  __syncthreads();

  constexpr int CT = C / 32;
  int wave = t >> 6, lane = t & 63;
  int wr = wave >> 1, wc = wave & 1;
  int quad = lane >> 4, ml = lane & 15;
  f32x4 acc[4][CT];
#pragma unroll
  for (int a = 0; a < 4; ++a)
#pragma unroll
    for (int b = 0; b < CT; ++b)
#pragma unroll
      for (int r = 0; r < 4; ++r) acc[a][b][r] = 0.f;
#pragma unroll
  for (int ks = 0; ks < 4; ++ks) {
    short8 af[4], bf8[CT];
#pragma unroll
    for (int rt = 0; rt < 4; ++rt)
      af[rt] = *(const short8*)&P[(wr * 64 + rt * 16 + ml) * KP + ks * 32 + quad * 8];
#pragma unroll
    for (int ct = 0; ct < CT; ++ct) {
      int cdim = wc * (C / 2) + ct * 16 + ml;
      int msk = ((cdim >> 3) & 15) << 3;
      bf8[ct] = *(const short8*)&Ht[cdim * KP + ((ks * 32 + quad * 8) ^ msk)];
    }
#pragma unroll
    for (int rt = 0; rt < 4; ++rt)
#pragma unroll
      for (int ct = 0; ct < CT; ++ct)
        acc[rt][ct] = __builtin_amdgcn_mfma_f32_16x16x32_bf16(af[rt], bf8[ct], acc[rt][ct], 0, 0, 0);
  }
#pragma unroll
  for (int rt = 0; rt < 4; ++rt) {
    int m2 = wr * 64 + rt * 16 + quad * 4;
#pragma unroll
    for (int r = 0; r < 4; ++r) {
      if (m2 + r < NREG) {
#pragma unroll
        for (int ct = 0; ct < CT; ++ct) {
          int n = wc * (C / 2) + ct * 16 + ml;
          Y[(size_t)(gbase + m2 + r) * D + h * C + n] = f2b(acc[rt][ct][r]);
        }
      }
    }
  }
}

// ---------------- bias + ELU + LN (concat layers) + next-layer weight transpose ----------------
// Role grid: blocks [0,464) do LN over D (and zero al/ar for the next gemm's
// atomics); blocks [464, 464 + (TK/32)*(TN/32)) transpose W[TK][TN] -> Wt.
// Transpose here is hazard-safe: runs after the last Hb reader (aggm) and
// before the consuming gemm (R13 fix for the R12 clobber bug).
template<int D, int TK, int TN>
__global__ __launch_bounds__(256) void k_ln(bf16* __restrict__ X, const void* __restrict__ bias,
                                            const void* __restrict__ ls, const void* __restrict__ lb,
                                            float* __restrict__ al, float* __restrict__ ar,
                                            const void* __restrict__ W, bf16* __restrict__ Wt,
                                            const int* __restrict__ flags) {
  __shared__ float tile[32][33];
  int bid = blockIdx.x;
  if (bid >= 464) {                       // transpose role
    int id = bid - 464;
    dev_transpose(W, Wt, TK, TN, id % (TK / 32), id / (TK / 32), flags[1], tile);
    return;
  }
  int gid = bid * 256 + threadIdx.x;
  if (gid < NN * 8) { al[gid] = 0.f; ar[gid] = 0.f; }
  int wF = flags[1];
  constexpr int VPT = D / 256;            // short8s per thread (8 or 4)
  int t = threadIdx.x;
  int nb = (bid & 7) * 58 + (bid >> 3);
  int node = nb * 8 + (t >> 5);
  int l32 = t & 31;
  float v[VPT * 8];
  float s1 = 0.f, s2 = 0.f;
#pragma unroll
  for (int j = 0; j < VPT; ++j) {
    int c0 = (l32 + j * 32) * 8;
    union { short8 u; short x[8]; } uu;
    uu.u = *(const short8*)&X[(size_t)node * D + c0];
    float bb[8];
    load8f(bias, c0, wF, bb);
#pragma unroll
    for (int k = 0; k < 8; ++k) {
      float vv = bits2f(uu.x[k]) + bb[k];
      vv = vv > 0.f ? vv : expf(vv) - 1.f;                  // ELU
      v[j * 8 + k] = vv; s1 += vv; s2 += vv * vv;
    }
  }
#pragma unroll
  for (int off = 16; off; off >>= 1) { s1 += __shfl_xor(s1, off); s2 += __shfl_xor(s2, off); }
  float mu = s1 / D;
  float rs = rsqrtf(s2 / D - mu * mu + 1e-5f);
#pragma unroll
  for (int j = 0; j < VPT; ++j) {
    int c0 = (l32 + j * 32) * 8;
    float g8[8], b8[8];
    load8f(ls, c0, wF, g8);
    load8f(lb, c0, wF, b8);
    union { short8 u; short x[8]; } uu;
#pragma unroll
    for (int k = 0; k < 8; ++k)
      uu.x[k] = f2bits((v[j * 8 + k] - mu) * rs * g8[k] + b8[k]);
    *(short8*)&X[(size_t)node * D + c0] = uu.u;
  }
}

// ---------------- gather-aggregate + mean + ELU + LN (layer 2) ----------------
__global__ void k_agg(const bf16* __restrict__ H, const float* __restrict__ al,
                      const float* __restrict__ ar, const float* __restrict__ mbuf,
                      const float* __restrict__ ibuf, const int* __restrict__ cnt,
                      const int* __restrict__ bucket, const void* __restrict__ bias,
                      const void* __restrict__ ls, const void* __restrict__ lb,
                      bf16* __restrict__ Xout, int C, int concat,
                      const int* __restrict__ flags) {
  int wF = flags[1];
  int bid = blockIdx.x;                   // grid NN = 8 * 464
  int d = (bid & 7) * 464 + (bid >> 3);
  int t = threadIdx.x;
  int D = 8 * C;
  __shared__ int sid[MAXDEG + 4];
  __shared__ float vals[512];

  int deg = cnt[d]; deg = deg > MAXDEG ? MAXDEG : deg;
  int total = deg + 1;
  int padded = (total + 3) & ~3;
  if (t < padded) sid[t] = t < deg ? bucket[d * MAXDEG + t] : d;
  __syncthreads();

  int i0 = t * 8;
  int hd = i0 / C;
  float m = mbuf[d * 8 + hd], inv = ibuf[d * 8 + hd], ard = ar[d * 8 + hd];

  float acc[8] = {0.f, 0.f, 0.f, 0.f, 0.f, 0.f, 0.f, 0.f};
  const bf16* __restrict__ Hp = H + i0;
  for (int eb = 0; eb < padded; eb += 4) {
    int s4[4]; float a4[4]; short8 u4[4];
#pragma unroll
    for (int j = 0; j < 4; ++j) s4[j] = sid[eb + j];
#pragma unroll
    for (int j = 0; j < 4; ++j) {
      a4[j] = al[s4[j] * 8 + hd];
      u4[j] = *(const short8*)&Hp[(size_t)s4[j] * D];
    }
#pragma unroll
    for (int j = 0; j < 4; ++j) {
      float lg = a4[j] + ard;
      lg = lg > 0.f ? lg : 0.2f * lg;
      float we = (eb + j) < total ? expf(lg - m) * inv : 0.f;
      union { short8 v; short s[8]; } uu; uu.v = u4[j];
#pragma unroll
      for (int k2 = 0; k2 < 8; ++k2) acc[k2] = fmaf(we, bits2f(uu.s[k2]), acc[k2]);
    }
  }

  // layer 2 path: 64 threads, one wave; mean over 8 heads -> 64 dims, ELU, LN over 64
#pragma unroll
  for (int j = 0; j < 8; ++j) vals[i0 + j] = acc[j];
  __syncthreads();
  float v = 0.f;
#pragma unroll
  for (int h = 0; h < 8; ++h) v += vals[h * 64 + t];
  v = v * 0.125f + ldsel(bias, t, wF);
  v = v > 0.f ? v : expf(v) - 1.f;
  float s1 = v, s2 = v * v;
#pragma unroll
  for (int off = 32; off; off >>= 1) { s1 += __shfl_xor(s1, off); s2 += __shfl_xor(s2, off); }
  float mu = s1 * (1.f / 64.f);
  float var = s2 * (1.f / 64.f) - mu * mu;
  float rs = rsqrtf(var + 1e-5f);
  Xout[(size_t)d * 64 + t] = f2b((v - mu) * rs * ldsel(ls, t, wF) + ldsel(lb, t, wF));
}

// ---------------- projection (64->256) + LN + GELU(erf) + q ----------------
__global__ __launch_bounds__(256) void k_proj(const bf16* __restrict__ X3, const void* __restrict__ wp,
                                              const void* __restrict__ bp, const void* __restrict__ lsp,
                                              const void* __restrict__ lbp, const void* __restrict__ wq,
                                              const void* __restrict__ bq,
                                              float* __restrict__ q, void* __restrict__ dout,
                                              const int* __restrict__ flags) {
  int wF = flags[1], xF = flags[0];
  int bid = blockIdx.x;
  int n = (bid & 7) * 464 + (bid >> 3);
  int t = threadIdx.x;
  int lane = t & 63, wave = t >> 6;
  __shared__ float xs[64];
  __shared__ float r1[4], r2[4];
  __shared__ float sMu, sRs;
  if (t < 64) xs[t] = b2f(X3[n * 64 + t]);
  __syncthreads();
  float y = ldsel(bp, t, wF);
#pragma unroll 8
  for (int k = 0; k < 64; ++k) y = fmaf(xs[k], ldsel(wp, k * 256 + t, wF), y);
  float s1 = y, s2 = y * y;
#pragma unroll
  for (int off = 32; off; off >>= 1) { s1 += __shfl_down(s1, off); s2 += __shfl_down(s2, off); }
  if (lane == 0) { r1[wave] = s1; r2[wave] = s2; }
  __syncthreads();
  if (t == 0) {
    float S1 = r1[0] + r1[1] + r1[2] + r1[3];
    float S2 = r2[0] + r2[1] + r2[2] + r2[3];
    float mu = S1 / 256.f;
    sMu = mu; sRs = rsqrtf(S2 / 256.f - mu * mu + 1e-5f);
  }
  __syncthreads();
  float v = (y - sMu) * sRs * ldsel(lsp, t, wF) + ldsel(lbp, t, wF);
  float g = 0.5f * v * (1.f + erff(v * 0.70710678118654752f));   // exact GELU
  stsel(dout, (size_t)NG * 256 + (size_t)n * 256 + t, g, xF);    // node_out
  float qv = g * ldsel(wq, t, wF);
#pragma unroll
  for (int off = 32; off; off >>= 1) qv += __shfl_down(qv, off);
  if (lane == 0) r1[wave] = qv;
  __syncthreads();
  if (t == 0) q[n] = r1[0] + r1[1] + r1[2] + r1[3] + ldsel(bq, 0, wF);
}

// ---------------- attention pooling per graph ----------------
__global__ __launch_bounds__(256) void k_pool(void* __restrict__ dout, const float* __restrict__ q,
                                              const int* __restrict__ flags) {
  int xF = flags[0];
  int bid = blockIdx.x;
  int b = (bid & 7) * 4 + (bid >> 3);
  int t = threadIdx.x;
  __shared__ float es[NREG];
  __shared__ float sDen;
  if (t < NREG) es[t] = q[b * NREG + t];
  __syncthreads();
  if (t == 0) {
    float m = -1e30f;
    for (int i = 0; i < NREG; ++i) m = fmaxf(m, es[i]);
    float den = 0.f;
    for (int i = 0; i < NREG; ++i) { float e = expf(es[i] - m); es[i] = e; den += e; }
    sDen = den;
  }
  __syncthreads();
  float acc = 0.f;
  for (int i = 0; i < NREG; ++i)
    acc = fmaf(es[i], ldsel(dout, (size_t)NG * 256 + (size_t)(b * NREG + i) * 256 + t, xF), acc);
  stsel(dout, (size_t)b * 256 + t, acc / sDen, xF);
}

// ---------------- launcher ----------------
extern "C" void kernel_launch(void* const* d_in, const int* in_sizes, int n_in,
                              void* d_out, int out_size, void* d_ws, size_t ws_size,
                              hipStream_t stream) {
  const void* nf  = d_in[0];
  const int* src  = (const int*)d_in[1];
  const int* dst  = (const int*)d_in[2];
  const void *w0 = d_in[4],  *b0 = d_in[5],  *as0 = d_in[6], *ad0 = d_in[7],  *ls0 = d_in[8],  *lb0 = d_in[9];
  const void *w1 = d_in[10], *b1 = d_in[11], *as1 = d_in[12], *ad1 = d_in[13], *ls1 = d_in[14], *lb1 = d_in[15];
  const void *w2 = d_in[16], *b2 = d_in[17], *as2 = d_in[18], *ad2 = d_in[19], *ls2 = d_in[20], *lb2 = d_in[21];
  const void *wp = d_in[22], *bp = d_in[23], *lsp = d_in[24], *lbp = d_in[25], *wq = d_in[26], *bq = d_in[27];

  // workspace layout (unchanged)
  int* flags  = (int*)d_ws;
  float* al   = (float*)(flags + 4);
  float* ar   = al + NN * 8;
  int* cnt    = (int*)(ar + NN * 8);
  int* bucket = cnt + NN;
  float* q    = (float*)(bucket + NN * MAXDEG);
  bf16* X     = (bf16*)(q + NN);
  bf16* Hb    = X + (size_t)NN * 2048;

  // softmax-stat scratch in the dead node_out region of d_out (k_proj overwrites later)
  float* mbuf = (float*)d_out;
  float* ibuf = mbuf + NN * 8;

  // dead-region reuse for bf16 staging buffers:
  bf16* X0  = X;
  bf16* wt0 = X + (1 << 20);
  bf16* wt1 = Hb + (size_t)NN * 1024;     // written by k_ln<2048> role blocks (post-gemm0)
  bf16* wt2 = Hb + (size_t)NN * 512;      // written by k_ln<1024> role blocks (post-gemm1)

  // prep (2 dispatches): detect || cnt-zero, then scatter || tox0 || w0-transpose || al/ar-zero
  k_prep1<<<1 + (NN + 255) / 256, 256, 0, stream>>>(nf, w0, flags, cnt);
  k_prep2<<<145 + NN + 512 + 116, 256, 0, stream>>>(
      src, dst, cnt, bucket, nf, X0, w0, wt0, al, ar, flags);

  // layer 0: 256 -> 8x256 concat (2048); gemm fills al/ar in epilogue
  k_gemm_mfma<<<(2048 / 64) * (NN / 64), 256, 0, stream>>>(X0, wt0, Hb, NN, 2048, 256,
                                                           as0, ad0, al, ar, 256, flags);
  k_edgew<<<NN / 4, 256, 0, stream>>>(al, ar, cnt, bucket, mbuf, ibuf);
  k_aggm<256><<<256, 256, 0, stream>>>(Hb, al, ar, mbuf, ibuf, cnt, bucket, X);
  // LN + w1 transpose (2048 role blocks): safe post-aggm, pre-gemm1
  k_ln<2048, 2048, 1024><<<464 + 2048, 256, 0, stream>>>(X, b0, ls0, lb0, al, ar, w1, wt1, flags);

  // layer 1: 2048 -> 8x128 concat (1024)
  k_gemm_mfma<<<(1024 / 64) * (NN / 64), 256, 0, stream>>>(X, wt1, Hb, NN, 1024, 2048,
                                                           as1, ad1, al, ar, 128, flags);
  k_edgew<<<NN / 4, 256, 0, stream>>>(al, ar, cnt, bucket, mbuf, ibuf);
  k_aggm<128><<<256, 256, 0, stream>>>(Hb, al, ar, mbuf, ibuf, cnt, bucket, X);
  // LN + w2 transpose (512 role blocks): safe post-aggm, pre-gemm2
  k_ln<1024, 1024, 512><<<464 + 512, 256, 0, stream>>>(X, b1, ls1, lb1, al, ar, w2, wt2, flags);

  // layer 2: 1024 -> 8x64 mean (64) — gather path (measured-good R8/R11)
  k_gemm_mfma<<<(512 / 64) * (NN / 64), 256, 0, stream>>>(X, wt2, Hb, NN, 512, 1024,
                                                          as2, ad2, al, ar, 64, flags);
  k_edgew<<<NN / 4, 256, 0, stream>>>(al, ar, cnt, bucket, mbuf, ibuf);
  k_agg<<<NN, 64, 0, stream>>>(Hb, al, ar, mbuf, ibuf, cnt, bucket, b2, ls2, lb2, X, 64, 0, flags);

  // projection + GELU + q, then pooling (node_out lives in d_out)
  k_proj<<<NN, 256, 0, stream>>>(X, wp, bp, lsp, lbp, wq, bq, q, d_out, flags);
  k_pool<<<NG, 256, 0, stream>>>(d_out, q, flags);
}

// Round 14
// 311.939 us; speedup vs baseline: 1.0936x; 1.0936x over previous
//
#include <hip/hip_runtime.h>
#include <hip/hip_bf16.h>
#include <math.h>

typedef __hip_bfloat16 bf16;
typedef short short8 __attribute__((ext_vector_type(8)));
typedef float f32x4 __attribute__((ext_vector_type(4)));

__device__ __forceinline__ float b2f(const bf16 v) { return __bfloat162float(v); }
__device__ __forceinline__ bf16 f2b(const float v) { return __float2bfloat16(v); }

// raw-bits bf16 -> f32
__device__ __forceinline__ float bits2f(short s) {
  unsigned u = ((unsigned)(unsigned short)s) << 16;
  float f;
  __builtin_memcpy(&f, &u, 4);
  return f;
}
__device__ __forceinline__ short f2bits(float f) {
  bf16 b = f2b(f);
  short s;
  __builtin_memcpy(&s, &b, 2);
  return s;
}

// dtype-flexible load/store: f32 flag selects float32 vs bfloat16 interpretation
__device__ __forceinline__ float ldsel(const void* p, size_t i, int f32) {
  return f32 ? ((const float*)p)[i] : b2f(((const bf16*)p)[i]);
}
__device__ __forceinline__ void stsel(void* p, size_t i, float v, int f32) {
  if (f32) ((float*)p)[i] = v; else ((bf16*)p)[i] = f2b(v);
}

// vectorized 8-wide dtype-flexible load
__device__ __forceinline__ void load8f(const void* p, int idx, int f32, float* o) {
  if (f32) {
    const float4* q = (const float4*)((const float*)p + idx);
    float4 a = q[0], b = q[1];
    o[0] = a.x; o[1] = a.y; o[2] = a.z; o[3] = a.w;
    o[4] = b.x; o[5] = b.y; o[6] = b.z; o[7] = b.w;
  } else {
    union { short8 v; short s[8]; } u;
    u.v = *(const short8*)((const bf16*)p + idx);
#pragma unroll
    for (int j = 0; j < 8; ++j) o[j] = bits2f(u.s[j]);
  }
}

#define NN 3712          // nodes
#define NE 37120         // edges (without self loops)
#define NG 32            // graphs
#define NREG 116         // nodes per graph
#define MAXDEG 48        // bucket capacity

// ---------------------------------------------------------------------------
// GLOBAL NODE->XCD PARTITION (verified R8: -57us): XCD x owns nodes
// [464x, 464(x+1)); (bid & 7) == owning XCD everywhere.
// R13 LESSON (2nd fusion regression): the gemm attention epilogue cost
// +10us/gemm — REVERTED to R11's separate plain-store k_attn (no atomics,
// no al/ar zeroing). KEPT: prep merges + k_ln transpose roles (hazard-safe,
// R13-verified correct). NEW (R14): gemm BK 64->128 — halves the serial
// barrier phases (latency-bound per counters: MfmaUtil 11%, all utils low),
// doubles loads in flight per phase; LDS 34.8KB, still grid-limited occupancy.
// ---------------------------------------------------------------------------

// ---------------- prep1: dtype detect || cnt zero ----------------
__global__ __launch_bounds__(256) void k_prep1(const void* nf, const void* w0,
                                               int* flags, int* cnt) {
  if (blockIdx.x == 0) {
    __shared__ int bad[2];
    if (threadIdx.x < 2) bad[threadIdx.x] = 0;
    __syncthreads();
    const bf16* a = (const bf16*)nf;
    const bf16* b = (const bf16*)w0;
    int l0 = 0, l1 = 0;
    for (int i = threadIdx.x; i < 4096; i += 256) {
      float x = b2f(a[i]); if (!(fabsf(x) < 1e4f)) l0++;
      float y = b2f(b[i]); if (!(fabsf(y) < 1e4f)) l1++;
    }
    if (l0) atomicAdd(&bad[0], l0);
    if (l1) atomicAdd(&bad[1], l1);
    __syncthreads();
    if (threadIdx.x == 0) { flags[0] = bad[0] > 0; flags[1] = bad[1] > 0; }
  } else {
    int i = (blockIdx.x - 1) * 256 + threadIdx.x;
    if (i < NN) cnt[i] = 0;
  }
}

// 32x32 transpose tile worker (all threads of a block take the same role branch)
__device__ __forceinline__ void dev_transpose(const void* W, bf16* Wt, int K, int N,
                                              int bx, int by, int f, float tile[32][33]) {
  int tx = threadIdx.x & 31, ty = threadIdx.x >> 5;
  int k0 = bx * 32, n0 = by * 32;
#pragma unroll
  for (int i = 0; i < 4; ++i)
    tile[ty + i * 8][tx] = ldsel(W, (size_t)(k0 + ty + i * 8) * N + n0 + tx, f);
  __syncthreads();
#pragma unroll
  for (int i = 0; i < 4; ++i)
    Wt[(size_t)(n0 + ty + i * 8) * K + k0 + tx] = f2b(tile[tx][ty + i * 8]);
}

// ---------------- prep2: scatter || tox0 || w0 transpose ----------------
// All roles independent; depend only on prep1. wt0 lives in the X region (safe:
// gemm0 is its only consumer and nothing writes X before gemm0).
// Grid = 145 + 3712 + 512 = 4369.
__global__ __launch_bounds__(256) void k_prep2(const int* __restrict__ src, const int* __restrict__ dst,
    int* __restrict__ cnt, int* __restrict__ bucket, const void* __restrict__ nf, bf16* __restrict__ X0,
    const void* __restrict__ w0, bf16* __restrict__ wt0, const int* __restrict__ flags) {
  __shared__ float tile[32][33];
  int id = blockIdx.x, t = threadIdx.x;
  if (id < 145) {                                   // edge scatter (NE = 145*256)
    int e = id * 256 + t;
    if (e < NE) {
      int d = dst[e], s = src[e];
      if ((unsigned)d < NN && (unsigned)s < NN) {
        int p = atomicAdd(&cnt[d], 1);
        if (p < MAXDEG) bucket[d * MAXDEG + p] = s;
      }
    }
  } else if ((id -= 145) < NN) {                    // input -> bf16, partition-aligned
    int f = flags[0];
    int n = (id & 7) * 464 + (id >> 3);
    int i = n * 256 + t;
    X0[i] = f2b(ldsel(nf, i, f));
  } else {                                          // w0: 256 x 2048
    id -= NN;
    dev_transpose(w0, wt0, 256, 2048, id & 7, id >> 3, flags[1], tile);
  }
}

// ---------------- MFMA bf16 NT GEMM: C[MxN] = A[MxK] * Bt[NxK]^T ----------------
// 64x64 tile, BK=128 (R14: halved barrier phases for the latency-bound K-loop),
// 4 waves (2x2), each wave 2x2 output tiles x 4 k-slices of 16x16x32 MFMA.
// LDS rows padded to 136 shorts (272B). Chunk swizzle == global node partition.
// K must be a multiple of 128 (256/2048/1024 all are).
__global__ __launch_bounds__(256) void k_gemm_mfma(const bf16* __restrict__ A, const bf16* __restrict__ Bt,
                                                   bf16* __restrict__ C, int M, int N, int K) {
  __shared__ short As[64 * 136];
  __shared__ short Bs[64 * 136];
  int tid = threadIdx.x;
  int wave = tid >> 6, lane = tid & 63;
  int wr = wave >> 1, wc = wave & 1;
  int quad = lane >> 4, ml = lane & 15;

  int nbx = N >> 6;
  int total = gridDim.x;
  int id = blockIdx.x;
  int tile = ((total & 7) == 0) ? ((id & 7) * (total >> 3) + (id >> 3)) : id;
  int n0 = (tile % nbx) << 6;
  int m0 = (tile / nbx) << 6;

  f32x4 acc[2][2];
#pragma unroll
  for (int rt = 0; rt < 2; ++rt)
#pragma unroll
    for (int ct = 0; ct < 2; ++ct)
#pragma unroll
      for (int r = 0; r < 4; ++r) acc[rt][ct][r] = 0.f;

  for (int k0 = 0; k0 < K; k0 += 128) {
    __syncthreads();                       // previous-iter LDS reads done
#pragma unroll
    for (int i = 0; i < 4; ++i) {
      int c = tid + (i << 8);              // 1024 16B-chunks per operand (64 rows x 16)
      int row = c >> 4, kg = (c & 15) << 3;
      *(uint4*)&As[row * 136 + kg] = *(const uint4*)&A[(size_t)(m0 + row) * K + k0 + kg];
      *(uint4*)&Bs[row * 136 + kg] = *(const uint4*)&Bt[(size_t)(n0 + row) * K + k0 + kg];
    }
    __syncthreads();
    short8 af[2][4], bfr[2][4];
#pragma unroll
    for (int rt = 0; rt < 2; ++rt)
#pragma unroll
      for (int kk = 0; kk < 4; ++kk)
        af[rt][kk] = *(const short8*)&As[(wr * 32 + rt * 16 + ml) * 136 + kk * 32 + quad * 8];
#pragma unroll
    for (int ct = 0; ct < 2; ++ct)
#pragma unroll
      for (int kk = 0; kk < 4; ++kk)
        bfr[ct][kk] = *(const short8*)&Bs[(wc * 32 + ct * 16 + ml) * 136 + kk * 32 + quad * 8];
#pragma unroll
    for (int rt = 0; rt < 2; ++rt)
#pragma unroll
      for (int ct = 0; ct < 2; ++ct)
#pragma unroll
        for (int kk = 0; kk < 4; ++kk)
          acc[rt][ct] = __builtin_amdgcn_mfma_f32_16x16x32_bf16(af[rt][kk], bfr[ct][kk], acc[rt][ct], 0, 0, 0);
  }
#pragma unroll
  for (int rt = 0; rt < 2; ++rt)
#pragma unroll
    for (int ct = 0; ct < 2; ++ct)
#pragma unroll
      for (int r = 0; r < 4; ++r) {
        int grow = m0 + wr * 32 + rt * 16 + quad * 4 + r;
        int gcol = n0 + wc * 32 + ct * 16 + ml;
        C[(size_t)grow * N + gcol] = f2b(acc[rt][ct][r]);
      }
}

// ---------------- attention coefficients al/ar: (N,8), 8 nodes per block ----------------
// Partition-aligned; plain stores (no atomics). R11-verified structure.
__global__ void k_attn(const bf16* __restrict__ H, const void* __restrict__ a_s,
                       const void* __restrict__ a_d, float* __restrict__ al,
                       float* __restrict__ ar, int C, const int* __restrict__ flags) {
  int wF = flags[1];
  int t = threadIdx.x;                     // blockDim = D/8
  int D = 8 * C;
  int i0 = t * 8;
  int bid = blockIdx.x;                    // grid 464 = 8 * 58
  int nb = (bid & 7) * 58 + (bid >> 3);
  float as8[8], ad8[8];
  load8f(a_s, i0, wF, as8);
  load8f(a_d, i0, wF, ad8);
  int G = C >> 3;
  int hd = i0 / C;
  for (int it = 0; it < 8; ++it) {
    int n = nb * 8 + it;
    union { short8 v; short s[8]; } u;
    u.v = *(const short8*)&H[(size_t)n * D + i0];
    float ps = 0.f, pd = 0.f;
#pragma unroll
    for (int j = 0; j < 8; ++j) {
      float h = bits2f(u.s[j]);
      ps = fmaf(h, as8[j], ps);
      pd = fmaf(h, ad8[j], pd);
    }
    for (int off = G >> 1; off; off >>= 1) {
      ps += __shfl_xor(ps, off);
      pd += __shfl_xor(pd, off);
    }
    if ((t & (G - 1)) == 0) {
      al[n * 8 + hd] = ps;
      ar[n * 8 + hd] = pd;
    }
  }
}

// ---------------- per-(dst,head) softmax max & 1/denominator ----------------
__global__ __launch_bounds__(256) void k_edgew(const float* __restrict__ al, const float* __restrict__ ar,
                                               const int* __restrict__ cnt, const int* __restrict__ bucket,
                                               float* __restrict__ mbuf, float* __restrict__ ibuf) {
  int t = threadIdx.x;
  int q = t >> 6, l = t & 63, hd = l >> 3, el = l & 7;
  int bid = blockIdx.x;                    // grid 928 = 8 * 116
  int d = (bid & 7) * 464 + (bid >> 3) * 4 + q;
  int deg = cnt[d]; deg = deg > MAXDEG ? MAXDEG : deg;
  int total = deg + 1;
  float ard = ar[d * 8 + hd];
  float lgv[7];
  float m = -1e30f;
#pragma unroll
  for (int k = 0; k < 7; ++k) {
    int e = el + k * 8;
    float lg = -1e30f;
    if (e < total) {
      int s = e < deg ? bucket[d * MAXDEG + e] : d;
      lg = al[s * 8 + hd] + ard;
      lg = lg > 0.f ? lg : 0.2f * lg;
    }
    lgv[k] = lg;
    m = fmaxf(m, lg);
  }
#pragma unroll
  for (int off = 4; off; off >>= 1) m = fmaxf(m, __shfl_xor(m, off));
  float den = 0.f;
#pragma unroll
  for (int k = 0; k < 7; ++k) den += (lgv[k] > -1e29f) ? expf(lgv[k] - m) : 0.f;
#pragma unroll
  for (int off = 4; off; off >>= 1) den += __shfl_xor(den, off);
  if (el == 0) { mbuf[d * 8 + hd] = m; ibuf[d * 8 + hd] = 1.f / den; }
}

// ---------------- MFMA aggregation: per (graph, head) block ----------------
// X_g[dst, h*C:...] = P_gh (116x116, LDS, bf16) @ H_g[:, h*C:...] (LDS, transposed).
// R11-verified: Ht column XOR-swizzle SW(c,s) = s ^ (((c>>3)&15)<<3) kills the
// 32-way transposed-staging bank conflict (7.7M -> ~0 cycles).
template<int C>
__global__ __launch_bounds__(256, 1) void k_aggm(const bf16* __restrict__ H,
    const float* __restrict__ al, const float* __restrict__ ar,
    const float* __restrict__ mbuf, const float* __restrict__ ibuf,
    const int* __restrict__ cnt, const int* __restrict__ bucket,
    bf16* __restrict__ Y) {
  constexpr int D = 8 * C;
  constexpr int KP = 136;                 // padded K row (shorts)
  __shared__ short P[128 * KP];
  __shared__ short Ht[C * KP];
  int t = threadIdx.x;
  int bid = blockIdx.x;                   // grid 256 = 8 XCD * 4 graphs * 8 heads
  int x = bid & 7, j = bid >> 3;
  int g = x * 4 + (j & 3);
  int h = j >> 2;
  int gbase = g * NREG;

  short8 z = {0, 0, 0, 0, 0, 0, 0, 0};
  for (int i = t; i < 128 * KP / 8; i += 256) *(short8*)&P[i * 8] = z;
  for (int i = t; i < C * 12; i += 256) {
    int c = i / 12, s = 116 + i % 12;
    Ht[c * KP + (s ^ (((c >> 3) & 15) << 3))] = 0;
  }
  __syncthreads();

  constexpr int CH = C / 8;
  for (int idx = t; idx < NREG * CH; idx += 256) {
    int s = idx / CH, c0 = (idx % CH) * 8;
    int msk = ((idx % CH) & 15) << 3;
    int sw = s ^ msk;
    union { short8 v; short x2[8]; } u;
    u.v = *(const short8*)&H[(size_t)(gbase + s) * D + h * C + c0];
#pragma unroll
    for (int jj = 0; jj < 8; ++jj) Ht[(c0 + jj) * KP + sw] = u.x2[jj];
  }
  if (t < NREG) {
    int gd = gbase + t;
    int deg = cnt[gd]; deg = deg > MAXDEG ? MAXDEG : deg;
    int total = deg + 1;
    float ard = ar[gd * 8 + h];
    float mm = mbuf[gd * 8 + h], inv = ibuf[gd * 8 + h];
    for (int base = 0; base < total; base += 8) {
      int sg[8]; float av[8];
#pragma unroll
      for (int jj = 0; jj < 8; ++jj) {
        int e = base + jj;
        sg[jj] = (e < deg) ? bucket[gd * MAXDEG + e] : gd;
      }
#pragma unroll
      for (int jj = 0; jj < 8; ++jj) av[jj] = al[sg[jj] * 8 + h];
#pragma unroll
      for (int jj = 0; jj < 8; ++jj) {
        if (base + jj < total) {
          float lg = av[jj] + ard;
          lg = lg > 0.f ? lg : 0.2f * lg;
          float alpha = expf(lg - mm) * inv;
          int off = t * KP + (sg[jj] - gbase);
          P[off] = f2bits(bits2f(P[off]) + alpha);
        }
      }
    }
  }
  __syncthreads();

  constexpr int CT = C / 32;
  int wave = t >> 6, lane = t & 63;
  int wr = wave >> 1, wc = wave & 1;
  int quad = lane >> 4, ml = lane & 15;
  f32x4 acc[4][CT];
#pragma unroll
  for (int a = 0; a < 4; ++a)
#pragma unroll
    for (int b = 0; b < CT; ++b)
#pragma unroll
      for (int r = 0; r < 4; ++r) acc[a][b][r] = 0.f;
#pragma unroll
  for (int ks = 0; ks < 4; ++ks) {
    short8 af[4], bf8[CT];
#pragma unroll
    for (int rt = 0; rt < 4; ++rt)
      af[rt] = *(const short8*)&P[(wr * 64 + rt * 16 + ml) * KP + ks * 32 + quad * 8];
#pragma unroll
    for (int ct = 0; ct < CT; ++ct) {
      int cdim = wc * (C / 2) + ct * 16 + ml;
      int msk = ((cdim >> 3) & 15) << 3;
      bf8[ct] = *(const short8*)&Ht[cdim * KP + ((ks * 32 + quad * 8) ^ msk)];
    }
#pragma unroll
    for (int rt = 0; rt < 4; ++rt)
#pragma unroll
      for (int ct = 0; ct < CT; ++ct)
        acc[rt][ct] = __builtin_amdgcn_mfma_f32_16x16x32_bf16(af[rt], bf8[ct], acc[rt][ct], 0, 0, 0);
  }
#pragma unroll
  for (int rt = 0; rt < 4; ++rt) {
    int m2 = wr * 64 + rt * 16 + quad * 4;
#pragma unroll
    for (int r = 0; r < 4; ++r) {
      if (m2 + r < NREG) {
#pragma unroll
        for (int ct = 0; ct < CT; ++ct) {
          int n = wc * (C / 2) + ct * 16 + ml;
          Y[(size_t)(gbase + m2 + r) * D + h * C + n] = f2b(acc[rt][ct][r]);
        }
      }
    }
  }
}

// ---------------- bias + ELU + LN (concat layers) + next-layer weight transpose ----------------
// Role grid: blocks [0,464) do LN over D; blocks [464, 464 + (TK/32)*(TN/32))
// transpose W[TK][TN] -> Wt. Hazard-safe: runs after the last Hb reader (aggm)
// and before the consuming gemm (R13-verified).
template<int D, int TK, int TN>
__global__ __launch_bounds__(256) void k_ln(bf16* __restrict__ X, const void* __restrict__ bias,
                                            const void* __restrict__ ls, const void* __restrict__ lb,
                                            const void* __restrict__ W, bf16* __restrict__ Wt,
                                            const int* __restrict__ flags) {
  __shared__ float tile[32][33];
  int bid = blockIdx.x;
  if (bid >= 464) {                       // transpose role
    int id = bid - 464;
    dev_transpose(W, Wt, TK, TN, id % (TK / 32), id / (TK / 32), flags[1], tile);
    return;
  }
  int wF = flags[1];
  constexpr int VPT = D / 256;            // short8s per thread (8 or 4)
  int t = threadIdx.x;
  int nb = (bid & 7) * 58 + (bid >> 3);
  int node = nb * 8 + (t >> 5);
  int l32 = t & 31;
  float v[VPT * 8];
  float s1 = 0.f, s2 = 0.f;
#pragma unroll
  for (int j = 0; j < VPT; ++j) {
    int c0 = (l32 + j * 32) * 8;
    union { short8 u; short x[8]; } uu;
    uu.u = *(const short8*)&X[(size_t)node * D + c0];
    float bb[8];
    load8f(bias, c0, wF, bb);
#pragma unroll
    for (int k = 0; k < 8; ++k) {
      float vv = bits2f(uu.x[k]) + bb[k];
      vv = vv > 0.f ? vv : expf(vv) - 1.f;                  // ELU
      v[j * 8 + k] = vv; s1 += vv; s2 += vv * vv;
    }
  }
#pragma unroll
  for (int off = 16; off; off >>= 1) { s1 += __shfl_xor(s1, off); s2 += __shfl_xor(s2, off); }
  float mu = s1 / D;
  float rs = rsqrtf(s2 / D - mu * mu + 1e-5f);
#pragma unroll
  for (int j = 0; j < VPT; ++j) {
    int c0 = (l32 + j * 32) * 8;
    float g8[8], b8[8];
    load8f(ls, c0, wF, g8);
    load8f(lb, c0, wF, b8);
    union { short8 u; short x[8]; } uu;
#pragma unroll
    for (int k = 0; k < 8; ++k)
      uu.x[k] = f2bits((v[j * 8 + k] - mu) * rs * g8[k] + b8[k]);
    *(short8*)&X[(size_t)node * D + c0] = uu.u;
  }
}

// ---------------- gather-aggregate + mean + ELU + LN (layer 2) ----------------
__global__ void k_agg(const bf16* __restrict__ H, const float* __restrict__ al,
                      const float* __restrict__ ar, const float* __restrict__ mbuf,
                      const float* __restrict__ ibuf, const int* __restrict__ cnt,
                      const int* __restrict__ bucket, const void* __restrict__ bias,
                      const void* __restrict__ ls, const void* __restrict__ lb,
                      bf16* __restrict__ Xout, int C, int concat,
                      const int* __restrict__ flags) {
  int wF = flags[1];
  int bid = blockIdx.x;                   // grid NN = 8 * 464
  int d = (bid & 7) * 464 + (bid >> 3);
  int t = threadIdx.x;
  int D = 8 * C;
  __shared__ int sid[MAXDEG + 4];
  __shared__ float vals[512];

  int deg = cnt[d]; deg = deg > MAXDEG ? MAXDEG : deg;
  int total = deg + 1;
  int padded = (total + 3) & ~3;
  if (t < padded) sid[t] = t < deg ? bucket[d * MAXDEG + t] : d;
  __syncthreads();

  int i0 = t * 8;
  int hd = i0 / C;
  float m = mbuf[d * 8 + hd], inv = ibuf[d * 8 + hd], ard = ar[d * 8 + hd];

  float acc[8] = {0.f, 0.f, 0.f, 0.f, 0.f, 0.f, 0.f, 0.f};
  const bf16* __restrict__ Hp = H + i0;
  for (int eb = 0; eb < padded; eb += 4) {
    int s4[4]; float a4[4]; short8 u4[4];
#pragma unroll
    for (int j = 0; j < 4; ++j) s4[j] = sid[eb + j];
#pragma unroll
    for (int j = 0; j < 4; ++j) {
      a4[j] = al[s4[j] * 8 + hd];
      u4[j] = *(const short8*)&Hp[(size_t)s4[j] * D];
    }
#pragma unroll
    for (int j = 0; j < 4; ++j) {
      float lg = a4[j] + ard;
      lg = lg > 0.f ? lg : 0.2f * lg;
      float we = (eb + j) < total ? expf(lg - m) * inv : 0.f;
      union { short8 v; short s[8]; } uu; uu.v = u4[j];
#pragma unroll
      for (int k2 = 0; k2 < 8; ++k2) acc[k2] = fmaf(we, bits2f(uu.s[k2]), acc[k2]);
    }
  }

  // layer 2 path: 64 threads, one wave; mean over 8 heads -> 64 dims, ELU, LN over 64
#pragma unroll
  for (int j = 0; j < 8; ++j) vals[i0 + j] = acc[j];
  __syncthreads();
  float v = 0.f;
#pragma unroll
  for (int h = 0; h < 8; ++h) v += vals[h * 64 + t];
  v = v * 0.125f + ldsel(bias, t, wF);
  v = v > 0.f ? v : expf(v) - 1.f;
  float s1 = v, s2 = v * v;
#pragma unroll
  for (int off = 32; off; off >>= 1) { s1 += __shfl_xor(s1, off); s2 += __shfl_xor(s2, off); }
  float mu = s1 * (1.f / 64.f);
  float var = s2 * (1.f / 64.f) - mu * mu;
  float rs = rsqrtf(var + 1e-5f);
  Xout[(size_t)d * 64 + t] = f2b((v - mu) * rs * ldsel(ls, t, wF) + ldsel(lb, t, wF));
}

// ---------------- projection (64->256) + LN + GELU(erf) + q ----------------
__global__ __launch_bounds__(256) void k_proj(const bf16* __restrict__ X3, const void* __restrict__ wp,
                                              const void* __restrict__ bp, const void* __restrict__ lsp,
                                              const void* __restrict__ lbp, const void* __restrict__ wq,
                                              const void* __restrict__ bq,
                                              float* __restrict__ q, void* __restrict__ dout,
                                              const int* __restrict__ flags) {
  int wF = flags[1], xF = flags[0];
  int bid = blockIdx.x;
  int n = (bid & 7) * 464 + (bid >> 3);
  int t = threadIdx.x;
  int lane = t & 63, wave = t >> 6;
  __shared__ float xs[64];
  __shared__ float r1[4], r2[4];
  __shared__ float sMu, sRs;
  if (t < 64) xs[t] = b2f(X3[n * 64 + t]);
  __syncthreads();
  float y = ldsel(bp, t, wF);
#pragma unroll 8
  for (int k = 0; k < 64; ++k) y = fmaf(xs[k], ldsel(wp, k * 256 + t, wF), y);
  float s1 = y, s2 = y * y;
#pragma unroll
  for (int off = 32; off; off >>= 1) { s1 += __shfl_down(s1, off); s2 += __shfl_down(s2, off); }
  if (lane == 0) { r1[wave] = s1; r2[wave] = s2; }
  __syncthreads();
  if (t == 0) {
    float S1 = r1[0] + r1[1] + r1[2] + r1[3];
    float S2 = r2[0] + r2[1] + r2[2] + r2[3];
    float mu = S1 / 256.f;
    sMu = mu; sRs = rsqrtf(S2 / 256.f - mu * mu + 1e-5f);
  }
  __syncthreads();
  float v = (y - sMu) * sRs * ldsel(lsp, t, wF) + ldsel(lbp, t, wF);
  float g = 0.5f * v * (1.f + erff(v * 0.70710678118654752f));   // exact GELU
  stsel(dout, (size_t)NG * 256 + (size_t)n * 256 + t, g, xF);    // node_out
  float qv = g * ldsel(wq, t, wF);
#pragma unroll
  for (int off = 32; off; off >>= 1) qv += __shfl_down(qv, off);
  if (lane == 0) r1[wave] = qv;
  __syncthreads();
  if (t == 0) q[n] = r1[0] + r1[1] + r1[2] + r1[3] + ldsel(bq, 0, wF);
}

// ---------------- attention pooling per graph ----------------
__global__ __launch_bounds__(256) void k_pool(void* __restrict__ dout, const float* __restrict__ q,
                                              const int* __restrict__ flags) {
  int xF = flags[0];
  int bid = blockIdx.x;
  int b = (bid & 7) * 4 + (bid >> 3);
  int t = threadIdx.x;
  __shared__ float es[NREG];
  __shared__ float sDen;
  if (t < NREG) es[t] = q[b * NREG + t];
  __syncthreads();
  if (t == 0) {
    float m = -1e30f;
    for (int i = 0; i < NREG; ++i) m = fmaxf(m, es[i]);
    float den = 0.f;
    for (int i = 0; i < NREG; ++i) { float e = expf(es[i] - m); es[i] = e; den += e; }
    sDen = den;
  }
  __syncthreads();
  float acc = 0.f;
  for (int i = 0; i < NREG; ++i)
    acc = fmaf(es[i], ldsel(dout, (size_t)NG * 256 + (size_t)(b * NREG + i) * 256 + t, xF), acc);
  stsel(dout, (size_t)b * 256 + t, acc / sDen, xF);
}

// ---------------- launcher ----------------
extern "C" void kernel_launch(void* const* d_in, const int* in_sizes, int n_in,
                              void* d_out, int out_size, void* d_ws, size_t ws_size,
                              hipStream_t stream) {
  const void* nf  = d_in[0];
  const int* src  = (const int*)d_in[1];
  const int* dst  = (const int*)d_in[2];
  const void *w0 = d_in[4],  *b0 = d_in[5],  *as0 = d_in[6], *ad0 = d_in[7],  *ls0 = d_in[8],  *lb0 = d_in[9];
  const void *w1 = d_in[10], *b1 = d_in[11], *as1 = d_in[12], *ad1 = d_in[13], *ls1 = d_in[14], *lb1 = d_in[15];
  const void *w2 = d_in[16], *b2 = d_in[17], *as2 = d_in[18], *ad2 = d_in[19], *ls2 = d_in[20], *lb2 = d_in[21];
  const void *wp = d_in[22], *bp = d_in[23], *lsp = d_in[24], *lbp = d_in[25], *wq = d_in[26], *bq = d_in[27];

  // workspace layout (unchanged)
  int* flags  = (int*)d_ws;
  float* al   = (float*)(flags + 4);
  float* ar   = al + NN * 8;
  int* cnt    = (int*)(ar + NN * 8);
  int* bucket = cnt + NN;
  float* q    = (float*)(bucket + NN * MAXDEG);
  bf16* X     = (bf16*)(q + NN);
  bf16* Hb    = X + (size_t)NN * 2048;

  // softmax-stat scratch in the dead node_out region of d_out (k_proj overwrites later)
  float* mbuf = (float*)d_out;
  float* ibuf = mbuf + NN * 8;

  // dead-region reuse for bf16 staging buffers:
  bf16* X0  = X;
  bf16* wt0 = X + (1 << 20);
  bf16* wt1 = Hb + (size_t)NN * 1024;     // written by k_ln<2048> role blocks (post-gemm0)
  bf16* wt2 = Hb + (size_t)NN * 512;      // written by k_ln<1024> role blocks (post-gemm1)

  // prep (2 dispatches): detect || cnt-zero, then scatter || tox0 || w0-transpose
  k_prep1<<<1 + (NN + 255) / 256, 256, 0, stream>>>(nf, w0, flags, cnt);
  k_prep2<<<145 + NN + 512, 256, 0, stream>>>(src, dst, cnt, bucket, nf, X0, w0, wt0, flags);

  // layer 0: 256 -> 8x256 concat (2048)
  k_gemm_mfma<<<(2048 / 64) * (NN / 64), 256, 0, stream>>>(X0, wt0, Hb, NN, 2048, 256);
  k_attn<<<NN / 8, 256, 0, stream>>>(Hb, as0, ad0, al, ar, 256, flags);
  k_edgew<<<NN / 4, 256, 0, stream>>>(al, ar, cnt, bucket, mbuf, ibuf);
  k_aggm<256><<<256, 256, 0, stream>>>(Hb, al, ar, mbuf, ibuf, cnt, bucket, X);
  // LN + w1 transpose (2048 role blocks): safe post-aggm, pre-gemm1
  k_ln<2048, 2048, 1024><<<464 + 2048, 256, 0, stream>>>(X, b0, ls0, lb0, w1, wt1, flags);

  // layer 1: 2048 -> 8x128 concat (1024)
  k_gemm_mfma<<<(1024 / 64) * (NN / 64), 256, 0, stream>>>(X, wt1, Hb, NN, 1024, 2048);
  k_attn<<<NN / 8, 128, 0, stream>>>(Hb, as1, ad1, al, ar, 128, flags);
  k_edgew<<<NN / 4, 256, 0, stream>>>(al, ar, cnt, bucket, mbuf, ibuf);
  k_aggm<128><<<256, 256, 0, stream>>>(Hb, al, ar, mbuf, ibuf, cnt, bucket, X);
  // LN + w2 transpose (512 role blocks): safe post-aggm, pre-gemm2
  k_ln<1024, 1024, 512><<<464 + 512, 256, 0, stream>>>(X, b1, ls1, lb1, w2, wt2, flags);

  // layer 2: 1024 -> 8x64 mean (64) — gather path (measured-good R8/R11)
  k_gemm_mfma<<<(512 / 64) * (NN / 64), 256, 0, stream>>>(X, wt2, Hb, NN, 512, 1024);
  k_attn<<<NN / 8, 64, 0, stream>>>(Hb, as2, ad2, al, ar, 64, flags);
  k_edgew<<<NN / 4, 256, 0, stream>>>(al, ar, cnt, bucket, mbuf, ibuf);
  k_agg<<<NN, 64, 0, stream>>>(Hb, al, ar, mbuf, ibuf, cnt, bucket, b2, ls2, lb2, X, 64, 0, flags);

  // projection + GELU + q, then pooling (node_out lives in d_out)
  k_proj<<<NN, 256, 0, stream>>>(X, wp, bp, lsp, lbp, wq, bq, q, d_out, flags);
  k_pool<<<NG, 256, 0, stream>>>(d_out, q, flags);
}

// Round 15
// 308.679 us; speedup vs baseline: 1.1052x; 1.0106x over previous
//
#include <hip/hip_runtime.h>
#include <hip/hip_bf16.h>
#include <math.h>

typedef __hip_bfloat16 bf16;
typedef short short8 __attribute__((ext_vector_type(8)));
typedef float f32x4 __attribute__((ext_vector_type(4)));

__device__ __forceinline__ float b2f(const bf16 v) { return __bfloat162float(v); }
__device__ __forceinline__ bf16 f2b(const float v) { return __float2bfloat16(v); }

// raw-bits bf16 -> f32
__device__ __forceinline__ float bits2f(short s) {
  unsigned u = ((unsigned)(unsigned short)s) << 16;
  float f;
  __builtin_memcpy(&f, &u, 4);
  return f;
}
__device__ __forceinline__ short f2bits(float f) {
  bf16 b = f2b(f);
  short s;
  __builtin_memcpy(&s, &b, 2);
  return s;
}

// dtype-flexible load/store: f32 flag selects float32 vs bfloat16 interpretation
__device__ __forceinline__ float ldsel(const void* p, size_t i, int f32) {
  return f32 ? ((const float*)p)[i] : b2f(((const bf16*)p)[i]);
}
__device__ __forceinline__ void stsel(void* p, size_t i, float v, int f32) {
  if (f32) ((float*)p)[i] = v; else ((bf16*)p)[i] = f2b(v);
}

// vectorized 8-wide dtype-flexible load
__device__ __forceinline__ void load8f(const void* p, int idx, int f32, float* o) {
  if (f32) {
    const float4* q = (const float4*)((const float*)p + idx);
    float4 a = q[0], b = q[1];
    o[0] = a.x; o[1] = a.y; o[2] = a.z; o[3] = a.w;
    o[4] = b.x; o[5] = b.y; o[6] = b.z; o[7] = b.w;
  } else {
    union { short8 v; short s[8]; } u;
    u.v = *(const short8*)((const bf16*)p + idx);
#pragma unroll
    for (int j = 0; j < 8; ++j) o[j] = bits2f(u.s[j]);
  }
}

#define NN 3712          // nodes
#define NE 37120         // edges (without self loops)
#define NG 32            // graphs
#define NREG 116         // nodes per graph
#define MAXDEG 48        // bucket capacity

// ---------------------------------------------------------------------------
// GLOBAL NODE->XCD PARTITION (verified R8: -57us): XCD x owns nodes
// [464x, 464(x+1)); (bid & 7) == owning XCD everywhere.
// R14 verified: BK=128 gemm + separate k_attn -> 311.9us.
// R15: k_aggm occupancy 1 -> 2 blocks/CU by splitting each (graph, head)
// block into column-halves (CB=128): LDS 104KB -> 69.6KB, layer-0 grid
// 256 -> 512, __launch_bounds__(256,2). Same occupancy lever that fixed
// the gemm in R3->R4. Layers 0/1 now share one aggm kernel.
// ---------------------------------------------------------------------------

// ---------------- prep1: dtype detect || cnt zero ----------------
__global__ __launch_bounds__(256) void k_prep1(const void* nf, const void* w0,
                                               int* flags, int* cnt) {
  if (blockIdx.x == 0) {
    __shared__ int bad[2];
    if (threadIdx.x < 2) bad[threadIdx.x] = 0;
    __syncthreads();
    const bf16* a = (const bf16*)nf;
    const bf16* b = (const bf16*)w0;
    int l0 = 0, l1 = 0;
    for (int i = threadIdx.x; i < 4096; i += 256) {
      float x = b2f(a[i]); if (!(fabsf(x) < 1e4f)) l0++;
      float y = b2f(b[i]); if (!(fabsf(y) < 1e4f)) l1++;
    }
    if (l0) atomicAdd(&bad[0], l0);
    if (l1) atomicAdd(&bad[1], l1);
    __syncthreads();
    if (threadIdx.x == 0) { flags[0] = bad[0] > 0; flags[1] = bad[1] > 0; }
  } else {
    int i = (blockIdx.x - 1) * 256 + threadIdx.x;
    if (i < NN) cnt[i] = 0;
  }
}

// 32x32 transpose tile worker (all threads of a block take the same role branch)
__device__ __forceinline__ void dev_transpose(const void* W, bf16* Wt, int K, int N,
                                              int bx, int by, int f, float tile[32][33]) {
  int tx = threadIdx.x & 31, ty = threadIdx.x >> 5;
  int k0 = bx * 32, n0 = by * 32;
#pragma unroll
  for (int i = 0; i < 4; ++i)
    tile[ty + i * 8][tx] = ldsel(W, (size_t)(k0 + ty + i * 8) * N + n0 + tx, f);
  __syncthreads();
#pragma unroll
  for (int i = 0; i < 4; ++i)
    Wt[(size_t)(n0 + ty + i * 8) * K + k0 + tx] = f2b(tile[tx][ty + i * 8]);
}

// ---------------- prep2: scatter || tox0 || w0 transpose ----------------
// Grid = 145 + 3712 + 512 = 4369.
__global__ __launch_bounds__(256) void k_prep2(const int* __restrict__ src, const int* __restrict__ dst,
    int* __restrict__ cnt, int* __restrict__ bucket, const void* __restrict__ nf, bf16* __restrict__ X0,
    const void* __restrict__ w0, bf16* __restrict__ wt0, const int* __restrict__ flags) {
  __shared__ float tile[32][33];
  int id = blockIdx.x, t = threadIdx.x;
  if (id < 145) {                                   // edge scatter (NE = 145*256)
    int e = id * 256 + t;
    if (e < NE) {
      int d = dst[e], s = src[e];
      if ((unsigned)d < NN && (unsigned)s < NN) {
        int p = atomicAdd(&cnt[d], 1);
        if (p < MAXDEG) bucket[d * MAXDEG + p] = s;
      }
    }
  } else if ((id -= 145) < NN) {                    // input -> bf16, partition-aligned
    int f = flags[0];
    int n = (id & 7) * 464 + (id >> 3);
    int i = n * 256 + t;
    X0[i] = f2b(ldsel(nf, i, f));
  } else {                                          // w0: 256 x 2048
    id -= NN;
    dev_transpose(w0, wt0, 256, 2048, id & 7, id >> 3, flags[1], tile);
  }
}

// ---------------- MFMA bf16 NT GEMM: C[MxN] = A[MxK] * Bt[NxK]^T ----------------
// 64x64 tile, BK=128 (R14-verified), 4 waves (2x2). Chunk swizzle == node partition.
__global__ __launch_bounds__(256) void k_gemm_mfma(const bf16* __restrict__ A, const bf16* __restrict__ Bt,
                                                   bf16* __restrict__ C, int M, int N, int K) {
  __shared__ short As[64 * 136];
  __shared__ short Bs[64 * 136];
  int tid = threadIdx.x;
  int wave = tid >> 6, lane = tid & 63;
  int wr = wave >> 1, wc = wave & 1;
  int quad = lane >> 4, ml = lane & 15;

  int nbx = N >> 6;
  int total = gridDim.x;
  int id = blockIdx.x;
  int tile = ((total & 7) == 0) ? ((id & 7) * (total >> 3) + (id >> 3)) : id;
  int n0 = (tile % nbx) << 6;
  int m0 = (tile / nbx) << 6;

  f32x4 acc[2][2];
#pragma unroll
  for (int rt = 0; rt < 2; ++rt)
#pragma unroll
    for (int ct = 0; ct < 2; ++ct)
#pragma unroll
      for (int r = 0; r < 4; ++r) acc[rt][ct][r] = 0.f;

  for (int k0 = 0; k0 < K; k0 += 128) {
    __syncthreads();                       // previous-iter LDS reads done
#pragma unroll
    for (int i = 0; i < 4; ++i) {
      int c = tid + (i << 8);              // 1024 16B-chunks per operand (64 rows x 16)
      int row = c >> 4, kg = (c & 15) << 3;
      *(uint4*)&As[row * 136 + kg] = *(const uint4*)&A[(size_t)(m0 + row) * K + k0 + kg];
      *(uint4*)&Bs[row * 136 + kg] = *(const uint4*)&Bt[(size_t)(n0 + row) * K + k0 + kg];
    }
    __syncthreads();
    short8 af[2][4], bfr[2][4];
#pragma unroll
    for (int rt = 0; rt < 2; ++rt)
#pragma unroll
      for (int kk = 0; kk < 4; ++kk)
        af[rt][kk] = *(const short8*)&As[(wr * 32 + rt * 16 + ml) * 136 + kk * 32 + quad * 8];
#pragma unroll
    for (int ct = 0; ct < 2; ++ct)
#pragma unroll
      for (int kk = 0; kk < 4; ++kk)
        bfr[ct][kk] = *(const short8*)&Bs[(wc * 32 + ct * 16 + ml) * 136 + kk * 32 + quad * 8];
#pragma unroll
    for (int rt = 0; rt < 2; ++rt)
#pragma unroll
      for (int ct = 0; ct < 2; ++ct)
#pragma unroll
        for (int kk = 0; kk < 4; ++kk)
          acc[rt][ct] = __builtin_amdgcn_mfma_f32_16x16x32_bf16(af[rt][kk], bfr[ct][kk], acc[rt][ct], 0, 0, 0);
  }
#pragma unroll
  for (int rt = 0; rt < 2; ++rt)
#pragma unroll
    for (int ct = 0; ct < 2; ++ct)
#pragma unroll
      for (int r = 0; r < 4; ++r) {
        int grow = m0 + wr * 32 + rt * 16 + quad * 4 + r;
        int gcol = n0 + wc * 32 + ct * 16 + ml;
        C[(size_t)grow * N + gcol] = f2b(acc[rt][ct][r]);
      }
}

// ---------------- attention coefficients al/ar: (N,8), 8 nodes per block ----------------
// Partition-aligned; plain stores (no atomics). R11-verified structure.
__global__ void k_attn(const bf16* __restrict__ H, const void* __restrict__ a_s,
                       const void* __restrict__ a_d, float* __restrict__ al,
                       float* __restrict__ ar, int C, const int* __restrict__ flags) {
  int wF = flags[1];
  int t = threadIdx.x;                     // blockDim = D/8
  int D = 8 * C;
  int i0 = t * 8;
  int bid = blockIdx.x;                    // grid 464 = 8 * 58
  int nb = (bid & 7) * 58 + (bid >> 3);
  float as8[8], ad8[8];
  load8f(a_s, i0, wF, as8);
  load8f(a_d, i0, wF, ad8);
  int G = C >> 3;
  int hd = i0 / C;
  for (int it = 0; it < 8; ++it) {
    int n = nb * 8 + it;
    union { short8 v; short s[8]; } u;
    u.v = *(const short8*)&H[(size_t)n * D + i0];
    float ps = 0.f, pd = 0.f;
#pragma unroll
    for (int j = 0; j < 8; ++j) {
      float h = bits2f(u.s[j]);
      ps = fmaf(h, as8[j], ps);
      pd = fmaf(h, ad8[j], pd);
    }
    for (int off = G >> 1; off; off >>= 1) {
      ps += __shfl_xor(ps, off);
      pd += __shfl_xor(pd, off);
    }
    if ((t & (G - 1)) == 0) {
      al[n * 8 + hd] = ps;
      ar[n * 8 + hd] = pd;
    }
  }
}

// ---------------- per-(dst,head) softmax max & 1/denominator ----------------
__global__ __launch_bounds__(256) void k_edgew(const float* __restrict__ al, const float* __restrict__ ar,
                                               const int* __restrict__ cnt, const int* __restrict__ bucket,
                                               float* __restrict__ mbuf, float* __restrict__ ibuf) {
  int t = threadIdx.x;
  int q = t >> 6, l = t & 63, hd = l >> 3, el = l & 7;
  int bid = blockIdx.x;                    // grid 928 = 8 * 116
  int d = (bid & 7) * 464 + (bid >> 3) * 4 + q;
  int deg = cnt[d]; deg = deg > MAXDEG ? MAXDEG : deg;
  int total = deg + 1;
  float ard = ar[d * 8 + hd];
  float lgv[7];
  float m = -1e30f;
#pragma unroll
  for (int k = 0; k < 7; ++k) {
    int e = el + k * 8;
    float lg = -1e30f;
    if (e < total) {
      int s = e < deg ? bucket[d * MAXDEG + e] : d;
      lg = al[s * 8 + hd] + ard;
      lg = lg > 0.f ? lg : 0.2f * lg;
    }
    lgv[k] = lg;
    m = fmaxf(m, lg);
  }
#pragma unroll
  for (int off = 4; off; off >>= 1) m = fmaxf(m, __shfl_xor(m, off));
  float den = 0.f;
#pragma unroll
  for (int k = 0; k < 7; ++k) den += (lgv[k] > -1e29f) ? expf(lgv[k] - m) : 0.f;
#pragma unroll
  for (int off = 4; off; off >>= 1) den += __shfl_xor(den, off);
  if (el == 0) { mbuf[d * 8 + hd] = m; ibuf[d * 8 + hd] = 1.f / den; }
}

// ---------------- MFMA aggregation: per (graph, column-block) ----------------
// Y_g[dst, col0:col0+CB] = P_gh (116x116, LDS, bf16) @ H_g[:, col0:col0+CB].
// R15: CB=128 column-blocks -> LDS 69.6KB -> 2 blocks/CU (was 104KB, 1/CU).
// Grid = 8 XCD * 4 graphs * (D/CB) col-blocks; head h = col0/Chead (P-scatter
// duplicated x2 for Chead=256 — cheap vs the occupancy win).
// Ht column XOR-swizzle (R11-verified): SW(c,s) = s ^ (((c>>3)&15)<<3).
template<int CB>
__global__ __launch_bounds__(256, 2) void k_aggm(const bf16* __restrict__ H,
    const float* __restrict__ al, const float* __restrict__ ar,
    const float* __restrict__ mbuf, const float* __restrict__ ibuf,
    const int* __restrict__ cnt, const int* __restrict__ bucket,
    bf16* __restrict__ Y, int D, int Chead) {
  constexpr int KP = 136;                 // padded K row (shorts)
  __shared__ short P[128 * KP];           // 34.8 KB
  __shared__ short Ht[CB * KP];           // CB=128: 34.8 KB
  int t = threadIdx.x;
  int bid = blockIdx.x;                   // grid = 8 * 4 * (D/CB)
  int x = bid & 7, j = bid >> 3;
  int g = x * 4 + (j & 3);
  int cb = j >> 2;
  int col0 = cb * CB;
  int h = col0 / Chead;
  int gbase = g * NREG;

  short8 z = {0, 0, 0, 0, 0, 0, 0, 0};
  for (int i = t; i < 128 * KP / 8; i += 256) *(short8*)&P[i * 8] = z;
  for (int i = t; i < CB * 12; i += 256) {          // Ht logical pad cols [116,128)
    int c = i / 12, s = 116 + i % 12;
    Ht[c * KP + (s ^ (((c >> 3) & 15) << 3))] = 0;
  }
  __syncthreads();

  constexpr int CH = CB / 8;              // 16 chunks per row
  for (int idx = t; idx < NREG * CH; idx += 256) {
    int s = idx / CH, c0l = (idx % CH) * 8;
    int msk = ((idx % CH) & 15) << 3;
    int sw = s ^ msk;
    union { short8 v; short x2[8]; } u;
    u.v = *(const short8*)&H[(size_t)(gbase + s) * D + col0 + c0l];
#pragma unroll
    for (int jj = 0; jj < 8; ++jj) Ht[(c0l + jj) * KP + sw] = u.x2[jj];
  }
  if (t < NREG) {
    int gd = gbase + t;
    int deg = cnt[gd]; deg = deg > MAXDEG ? MAXDEG : deg;
    int total = deg + 1;
    float ard = ar[gd * 8 + h];
    float mm = mbuf[gd * 8 + h], inv = ibuf[gd * 8 + h];
    for (int base = 0; base < total; base += 8) {
      int sg[8]; float av[8];
#pragma unroll
      for (int jj = 0; jj < 8; ++jj) {
        int e = base + jj;
        sg[jj] = (e < deg) ? bucket[gd * MAXDEG + e] : gd;
      }
#pragma unroll
      for (int jj = 0; jj < 8; ++jj) av[jj] = al[sg[jj] * 8 + h];
#pragma unroll
      for (int jj = 0; jj < 8; ++jj) {
        if (base + jj < total) {
          float lg = av[jj] + ard;
          lg = lg > 0.f ? lg : 0.2f * lg;
          float alpha = expf(lg - mm) * inv;
          int off = t * KP + (sg[jj] - gbase);
          P[off] = f2bits(bits2f(P[off]) + alpha);
        }
      }
    }
  }
  __syncthreads();

  // MFMA: 4 waves 2x2; wave tile 64 rows x 64 cols; K=128 (116 + zero pad)
  constexpr int CT = 4;                   // 64/16 col tiles per wave
  int wave = t >> 6, lane = t & 63;
  int wr = wave >> 1, wc = wave & 1;
  int quad = lane >> 4, ml = lane & 15;
  f32x4 acc[4][CT];
#pragma unroll
  for (int a = 0; a < 4; ++a)
#pragma unroll
    for (int b = 0; b < CT; ++b)
#pragma unroll
      for (int r = 0; r < 4; ++r) acc[a][b][r] = 0.f;
#pragma unroll
  for (int ks = 0; ks < 4; ++ks) {
    short8 af[4], bf4[CT];
#pragma unroll
    for (int rt = 0; rt < 4; ++rt)
      af[rt] = *(const short8*)&P[(wr * 64 + rt * 16 + ml) * KP + ks * 32 + quad * 8];
#pragma unroll
    for (int ct = 0; ct < CT; ++ct) {
      int cdim = wc * 64 + ct * 16 + ml;
      int msk = ((cdim >> 3) & 15) << 3;
      bf4[ct] = *(const short8*)&Ht[cdim * KP + ((ks * 32 + quad * 8) ^ msk)];
    }
#pragma unroll
    for (int rt = 0; rt < 4; ++rt)
#pragma unroll
      for (int ct = 0; ct < CT; ++ct)
        acc[rt][ct] = __builtin_amdgcn_mfma_f32_16x16x32_bf16(af[rt], bf4[ct], acc[rt][ct], 0, 0, 0);
  }
#pragma unroll
  for (int rt = 0; rt < 4; ++rt) {
    int m2 = wr * 64 + rt * 16 + quad * 4;
#pragma unroll
    for (int r = 0; r < 4; ++r) {
      if (m2 + r < NREG) {
#pragma unroll
        for (int ct = 0; ct < CT; ++ct) {
          int n = wc * 64 + ct * 16 + ml;
          Y[(size_t)(gbase + m2 + r) * D + col0 + n] = f2b(acc[rt][ct][r]);
        }
      }
    }
  }
}

// ---------------- bias + ELU + LN (concat layers) + next-layer weight transpose ----------------
// Role grid: blocks [0,464) do LN over D; blocks [464, 464 + (TK/32)*(TN/32))
// transpose W[TK][TN] -> Wt (hazard-safe: post-aggm, pre-gemm; R13-verified).
template<int D, int TK, int TN>
__global__ __launch_bounds__(256) void k_ln(bf16* __restrict__ X, const void* __restrict__ bias,
                                            const void* __restrict__ ls, const void* __restrict__ lb,
                                            const void* __restrict__ W, bf16* __restrict__ Wt,
                                            const int* __restrict__ flags) {
  __shared__ float tile[32][33];
  int bid = blockIdx.x;
  if (bid >= 464) {                       // transpose role
    int id = bid - 464;
    dev_transpose(W, Wt, TK, TN, id % (TK / 32), id / (TK / 32), flags[1], tile);
    return;
  }
  int wF = flags[1];
  constexpr int VPT = D / 256;            // short8s per thread (8 or 4)
  int t = threadIdx.x;
  int nb = (bid & 7) * 58 + (bid >> 3);
  int node = nb * 8 + (t >> 5);
  int l32 = t & 31;
  float v[VPT * 8];
  float s1 = 0.f, s2 = 0.f;
#pragma unroll
  for (int j = 0; j < VPT; ++j) {
    int c0 = (l32 + j * 32) * 8;
    union { short8 u; short x[8]; } uu;
    uu.u = *(const short8*)&X[(size_t)node * D + c0];
    float bb[8];
    load8f(bias, c0, wF, bb);
#pragma unroll
    for (int k = 0; k < 8; ++k) {
      float vv = bits2f(uu.x[k]) + bb[k];
      vv = vv > 0.f ? vv : expf(vv) - 1.f;                  // ELU
      v[j * 8 + k] = vv; s1 += vv; s2 += vv * vv;
    }
  }
#pragma unroll
  for (int off = 16; off; off >>= 1) { s1 += __shfl_xor(s1, off); s2 += __shfl_xor(s2, off); }
  float mu = s1 / D;
  float rs = rsqrtf(s2 / D - mu * mu + 1e-5f);
#pragma unroll
  for (int j = 0; j < VPT; ++j) {
    int c0 = (l32 + j * 32) * 8;
    float g8[8], b8[8];
    load8f(ls, c0, wF, g8);
    load8f(lb, c0, wF, b8);
    union { short8 u; short x[8]; } uu;
#pragma unroll
    for (int k = 0; k < 8; ++k)
      uu.x[k] = f2bits((v[j * 8 + k] - mu) * rs * g8[k] + b8[k]);
    *(short8*)&X[(size_t)node * D + c0] = uu.u;
  }
}

// ---------------- gather-aggregate + mean + ELU + LN (layer 2) ----------------
__global__ void k_agg(const bf16* __restrict__ H, const float* __restrict__ al,
                      const float* __restrict__ ar, const float* __restrict__ mbuf,
                      const float* __restrict__ ibuf, const int* __restrict__ cnt,
                      const int* __restrict__ bucket, const void* __restrict__ bias,
                      const void* __restrict__ ls, const void* __restrict__ lb,
                      bf16* __restrict__ Xout, int C, int concat,
                      const int* __restrict__ flags) {
  int wF = flags[1];
  int bid = blockIdx.x;                   // grid NN = 8 * 464
  int d = (bid & 7) * 464 + (bid >> 3);
  int t = threadIdx.x;
  int D = 8 * C;
  __shared__ int sid[MAXDEG + 4];
  __shared__ float vals[512];

  int deg = cnt[d]; deg = deg > MAXDEG ? MAXDEG : deg;
  int total = deg + 1;
  int padded = (total + 3) & ~3;
  if (t < padded) sid[t] = t < deg ? bucket[d * MAXDEG + t] : d;
  __syncthreads();

  int i0 = t * 8;
  int hd = i0 / C;
  float m = mbuf[d * 8 + hd], inv = ibuf[d * 8 + hd], ard = ar[d * 8 + hd];

  float acc[8] = {0.f, 0.f, 0.f, 0.f, 0.f, 0.f, 0.f, 0.f};
  const bf16* __restrict__ Hp = H + i0;
  for (int eb = 0; eb < padded; eb += 4) {
    int s4[4]; float a4[4]; short8 u4[4];
#pragma unroll
    for (int j = 0; j < 4; ++j) s4[j] = sid[eb + j];
#pragma unroll
    for (int j = 0; j < 4; ++j) {
      a4[j] = al[s4[j] * 8 + hd];
      u4[j] = *(const short8*)&Hp[(size_t)s4[j] * D];
    }
#pragma unroll
    for (int j = 0; j < 4; ++j) {
      float lg = a4[j] + ard;
      lg = lg > 0.f ? lg : 0.2f * lg;
      float we = (eb + j) < total ? expf(lg - m) * inv : 0.f;
      union { short8 v; short s[8]; } uu; uu.v = u4[j];
#pragma unroll
      for (int k2 = 0; k2 < 8; ++k2) acc[k2] = fmaf(we, bits2f(uu.s[k2]), acc[k2]);
    }
  }

  // layer 2 path: 64 threads, one wave; mean over 8 heads -> 64 dims, ELU, LN over 64
#pragma unroll
  for (int j = 0; j < 8; ++j) vals[i0 + j] = acc[j];
  __syncthreads();
  float v = 0.f;
#pragma unroll
  for (int h = 0; h < 8; ++h) v += vals[h * 64 + t];
  v = v * 0.125f + ldsel(bias, t, wF);
  v = v > 0.f ? v : expf(v) - 1.f;
  float s1 = v, s2 = v * v;
#pragma unroll
  for (int off = 32; off; off >>= 1) { s1 += __shfl_xor(s1, off); s2 += __shfl_xor(s2, off); }
  float mu = s1 * (1.f / 64.f);
  float var = s2 * (1.f / 64.f) - mu * mu;
  float rs = rsqrtf(var + 1e-5f);
  Xout[(size_t)d * 64 + t] = f2b((v - mu) * rs * ldsel(ls, t, wF) + ldsel(lb, t, wF));
}

// ---------------- projection (64->256) + LN + GELU(erf) + q ----------------
__global__ __launch_bounds__(256) void k_proj(const bf16* __restrict__ X3, const void* __restrict__ wp,
                                              const void* __restrict__ bp, const void* __restrict__ lsp,
                                              const void* __restrict__ lbp, const void* __restrict__ wq,
                                              const void* __restrict__ bq,
                                              float* __restrict__ q, void* __restrict__ dout,
                                              const int* __restrict__ flags) {
  int wF = flags[1], xF = flags[0];
  int bid = blockIdx.x;
  int n = (bid & 7) * 464 + (bid >> 3);
  int t = threadIdx.x;
  int lane = t & 63, wave = t >> 6;
  __shared__ float xs[64];
  __shared__ float r1[4], r2[4];
  __shared__ float sMu, sRs;
  if (t < 64) xs[t] = b2f(X3[n * 64 + t]);
  __syncthreads();
  float y = ldsel(bp, t, wF);
#pragma unroll 8
  for (int k = 0; k < 64; ++k) y = fmaf(xs[k], ldsel(wp, k * 256 + t, wF), y);
  float s1 = y, s2 = y * y;
#pragma unroll
  for (int off = 32; off; off >>= 1) { s1 += __shfl_down(s1, off); s2 += __shfl_down(s2, off); }
  if (lane == 0) { r1[wave] = s1; r2[wave] = s2; }
  __syncthreads();
  if (t == 0) {
    float S1 = r1[0] + r1[1] + r1[2] + r1[3];
    float S2 = r2[0] + r2[1] + r2[2] + r2[3];
    float mu = S1 / 256.f;
    sMu = mu; sRs = rsqrtf(S2 / 256.f - mu * mu + 1e-5f);
  }
  __syncthreads();
  float v = (y - sMu) * sRs * ldsel(lsp, t, wF) + ldsel(lbp, t, wF);
  float g = 0.5f * v * (1.f + erff(v * 0.70710678118654752f));   // exact GELU
  stsel(dout, (size_t)NG * 256 + (size_t)n * 256 + t, g, xF);    // node_out
  float qv = g * ldsel(wq, t, wF);
#pragma unroll
  for (int off = 32; off; off >>= 1) qv += __shfl_down(qv, off);
  if (lane == 0) r1[wave] = qv;
  __syncthreads();
  if (t == 0) q[n] = r1[0] + r1[1] + r1[2] + r1[3] + ldsel(bq, 0, wF);
}

// ---------------- attention pooling per graph ----------------
__global__ __launch_bounds__(256) void k_pool(void* __restrict__ dout, const float* __restrict__ q,
                                              const int* __restrict__ flags) {
  int xF = flags[0];
  int bid = blockIdx.x;
  int b = (bid & 7) * 4 + (bid >> 3);
  int t = threadIdx.x;
  __shared__ float es[NREG];
  __shared__ float sDen;
  if (t < NREG) es[t] = q[b * NREG + t];
  __syncthreads();
  if (t == 0) {
    float m = -1e30f;
    for (int i = 0; i < NREG; ++i) m = fmaxf(m, es[i]);
    float den = 0.f;
    for (int i = 0; i < NREG; ++i) { float e = expf(es[i] - m); es[i] = e; den += e; }
    sDen = den;
  }
  __syncthreads();
  float acc = 0.f;
  for (int i = 0; i < NREG; ++i)
    acc = fmaf(es[i], ldsel(dout, (size_t)NG * 256 + (size_t)(b * NREG + i) * 256 + t, xF), acc);
  stsel(dout, (size_t)b * 256 + t, acc / sDen, xF);
}

// ---------------- launcher ----------------
extern "C" void kernel_launch(void* const* d_in, const int* in_sizes, int n_in,
                              void* d_out, int out_size, void* d_ws, size_t ws_size,
                              hipStream_t stream) {
  const void* nf  = d_in[0];
  const int* src  = (const int*)d_in[1];
  const int* dst  = (const int*)d_in[2];
  const void *w0 = d_in[4],  *b0 = d_in[5],  *as0 = d_in[6], *ad0 = d_in[7],  *ls0 = d_in[8],  *lb0 = d_in[9];
  const void *w1 = d_in[10], *b1 = d_in[11], *as1 = d_in[12], *ad1 = d_in[13], *ls1 = d_in[14], *lb1 = d_in[15];
  const void *w2 = d_in[16], *b2 = d_in[17], *as2 = d_in[18], *ad2 = d_in[19], *ls2 = d_in[20], *lb2 = d_in[21];
  const void *wp = d_in[22], *bp = d_in[23], *lsp = d_in[24], *lbp = d_in[25], *wq = d_in[26], *bq = d_in[27];

  // workspace layout (unchanged)
  int* flags  = (int*)d_ws;
  float* al   = (float*)(flags + 4);
  float* ar   = al + NN * 8;
  int* cnt    = (int*)(ar + NN * 8);
  int* bucket = cnt + NN;
  float* q    = (float*)(bucket + NN * MAXDEG);
  bf16* X     = (bf16*)(q + NN);
  bf16* Hb    = X + (size_t)NN * 2048;

  // softmax-stat scratch in the dead node_out region of d_out (k_proj overwrites later)
  float* mbuf = (float*)d_out;
  float* ibuf = mbuf + NN * 8;

  // dead-region reuse for bf16 staging buffers:
  bf16* X0  = X;
  bf16* wt0 = X + (1 << 20);
  bf16* wt1 = Hb + (size_t)NN * 1024;     // written by k_ln<2048> role blocks (post-gemm0)
  bf16* wt2 = Hb + (size_t)NN * 512;      // written by k_ln<1024> role blocks (post-gemm1)

  // prep (2 dispatches): detect || cnt-zero, then scatter || tox0 || w0-transpose
  k_prep1<<<1 + (NN + 255) / 256, 256, 0, stream>>>(nf, w0, flags, cnt);
  k_prep2<<<145 + NN + 512, 256, 0, stream>>>(src, dst, cnt, bucket, nf, X0, w0, wt0, flags);

  // layer 0: 256 -> 8x256 concat (2048)
  k_gemm_mfma<<<(2048 / 64) * (NN / 64), 256, 0, stream>>>(X0, wt0, Hb, NN, 2048, 256);
  k_attn<<<NN / 8, 256, 0, stream>>>(Hb, as0, ad0, al, ar, 256, flags);
  k_edgew<<<NN / 4, 256, 0, stream>>>(al, ar, cnt, bucket, mbuf, ibuf);
  k_aggm<128><<<8 * 4 * 16, 256, 0, stream>>>(Hb, al, ar, mbuf, ibuf, cnt, bucket, X, 2048, 256);
  // LN + w1 transpose (2048 role blocks): safe post-aggm, pre-gemm1
  k_ln<2048, 2048, 1024><<<464 + 2048, 256, 0, stream>>>(X, b0, ls0, lb0, w1, wt1, flags);

  // layer 1: 2048 -> 8x128 concat (1024)
  k_gemm_mfma<<<(1024 / 64) * (NN / 64), 256, 0, stream>>>(X, wt1, Hb, NN, 1024, 2048);
  k_attn<<<NN / 8, 128, 0, stream>>>(Hb, as1, ad1, al, ar, 128, flags);
  k_edgew<<<NN / 4, 256, 0, stream>>>(al, ar, cnt, bucket, mbuf, ibuf);
  k_aggm<128><<<8 * 4 * 8, 256, 0, stream>>>(Hb, al, ar, mbuf, ibuf, cnt, bucket, X, 1024, 128);
  // LN + w2 transpose (512 role blocks): safe post-aggm, pre-gemm2
  k_ln<1024, 1024, 512><<<464 + 512, 256, 0, stream>>>(X, b1, ls1, lb1, w2, wt2, flags);

  // layer 2: 1024 -> 8x64 mean (64) — gather path (measured-good R8/R11)
  k_gemm_mfma<<<(512 / 64) * (NN / 64), 256, 0, stream>>>(X, wt2, Hb, NN, 512, 1024);
  k_attn<<<NN / 8, 64, 0, stream>>>(Hb, as2, ad2, al, ar, 64, flags);
  k_edgew<<<NN / 4, 256, 0, stream>>>(al, ar, cnt, bucket, mbuf, ibuf);
  k_agg<<<NN, 64, 0, stream>>>(Hb, al, ar, mbuf, ibuf, cnt, bucket, b2, ls2, lb2, X, 64, 0, flags);

  // projection + GELU + q, then pooling (node_out lives in d_out)
  k_proj<<<NN, 256, 0, stream>>>(X, wp, bp, lsp, lbp, wq, bq, q, d_out, flags);
  k_pool<<<NG, 256, 0, stream>>>(d_out, q, flags);
}